// Round 3
// baseline (119.400 us; speedup 1.0000x reference)
//
#include <hip/hip_runtime.h>
#include <hip/hip_bf16.h>

#define NN 100000   // nodes
#define H  256      // feature dim
#define NE 300000   // edges
#define KOUT 512    // y row length (u | v)
#define MTILES 782  // ceil(NN/128)

typedef __attribute__((ext_vector_type(8))) short short8;
typedef __attribute__((ext_vector_type(8))) unsigned short ushort8v;
typedef __attribute__((ext_vector_type(4))) float f32x4;

__device__ __forceinline__ unsigned short f2bf(float f) {
    unsigned int u = __float_as_uint(f);
    u += 0x7FFFu + ((u >> 16) & 1u);   // RNE
    return (unsigned short)(u >> 16);
}
__device__ __forceinline__ float bf2f(unsigned short h) {
    return __uint_as_float(((unsigned int)h) << 16);
}
// byte offset into a [rows][64] bf16 tile image (128B rows), XOR-swizzled
__device__ __forceinline__ int swz(int row, int coloff) {
    return row * 128 + (coloff ^ ((row & 7) << 4));
}
// async global->LDS, 16B per lane; LDS dest is wave-uniform base + lane*16
__device__ __forceinline__ void gload16(const void* g, void* l) {
    __builtin_amdgcn_global_load_lds((const __attribute__((address_space(1))) void*)g,
                                     (__attribute__((address_space(3))) void*)l,
                                     16, 0, 0);
}

// ---------------- W-prep: W1 (fp32 [512][256]) -> 16 pre-swizzled bf16 tiles [128n][64k]
// tile t = nt*4+ks; element (n,kz) of tile stored at byte swz(n, kz*2).
__global__ __launch_bounds__(256) void wprep(const float* __restrict__ W1,
                                             unsigned short* __restrict__ wsB) {
    int gtid = blockIdx.x * 256 + threadIdx.x;   // 16384 threads
    int t  = gtid >> 10;
    int kg = (gtid >> 7) & 7;
    int n  = gtid & 127;
    int nt = t >> 2, ks = t & 3;
    int krow0 = ks * 64 + kg * 8 + ((nt >= 2) ? 256 : 0);
    int col = (nt & 1) * 128 + n;
    const float* src = W1 + (size_t)krow0 * 256 + col;
    ushort8v p;
    #pragma unroll
    for (int i = 0; i < 8; ++i) p[i] = f2bf(src[(size_t)i * 256]);
    *(ushort8v*)((char*)(wsB + t * 8192) + swz(n, kg * 16)) = p;
}

// ---------------- X-prep: x (fp32 [100000][256]) -> 3128 pre-swizzled bf16 A-tiles
// tile t = mt*4+ks: [128 rows][64 k], byte swz(r, kcol*2). Rows >= NN duplicate NN-1.
__global__ __launch_bounds__(256) void xprep(const float* __restrict__ x,
                                             unsigned short* __restrict__ xb) {
    int gid = blockIdx.x * 256 + threadIdx.x;   // 3,203,072 threads total
    int t   = gid >> 10;          // tile = mt*4+ks
    int r   = (gid >> 3) & 127;   // row in tile
    int cg  = gid & 7;            // 16B granule within 128B row
    int mt = t >> 2, ks = t & 3;
    int node = mt * 128 + r; if (node > NN - 1) node = NN - 1;
    const float* src = x + (size_t)node * H + ks * 64 + cg * 8;
    float4 v0 = *(const float4*)(src);
    float4 v1 = *(const float4*)(src + 4);
    ushort8v p;
    p[0]=f2bf(v0.x); p[1]=f2bf(v0.y); p[2]=f2bf(v0.z); p[3]=f2bf(v0.w);
    p[4]=f2bf(v1.x); p[5]=f2bf(v1.y); p[6]=f2bf(v1.z); p[7]=f2bf(v1.w);
    *(ushort8v*)((char*)(xb + (size_t)t * 8192) + swz(r, cg * 16)) = p;
}

// ---------------- Phase 1 v3: m97 structure — global_load_lds from pre-swizzled bf16
__global__ __launch_bounds__(256) void gemm_v3(const unsigned short* __restrict__ xb,
                                               const unsigned short* __restrict__ wsB,
                                               unsigned short* __restrict__ y) {
    __shared__ unsigned short Al[8192];  // 16KB swizzled image
    __shared__ unsigned short Bl[8192];
    const int tid = threadIdx.x;
    // bijective XCD swizzle: grid 3128 = 8 * 391
    const int logical = ((int)blockIdx.x & 7) * ((int)gridDim.x >> 3) + ((int)blockIdx.x >> 3);
    const int mt = logical >> 2, nt = logical & 3;
    const int m0 = mt * 128, n0 = nt * 128;
    const int lane = tid & 63, wid = tid >> 6;
    const int wm = (wid >> 1) * 64, wn = (wid & 1) * 64;
    const int lr = lane & 15, lk = lane >> 4;

    const char* asrc = (const char*)(xb + (size_t)mt * 4 * 8192) + wid * 4096 + lane * 16;
    const char* bsrc = (const char*)(wsB + nt * 4 * 8192) + wid * 4096 + lane * 16;
    char* adst = (char*)Al + wid * 4096;   // wave-uniform dest; HW adds lane*16
    char* bdst = (char*)Bl + wid * 4096;

    f32x4 acc[4][4] = {};
    #pragma unroll
    for (int ks = 0; ks < 4; ++ks) {
        if (ks) __syncthreads();            // all waves done reading previous tile
        #pragma unroll
        for (int i = 0; i < 4; ++i) {
            gload16(asrc + ks * 16384 + i * 1024, adst + i * 1024);
            gload16(bsrc + ks * 16384 + i * 1024, bdst + i * 1024);
        }
        __syncthreads();                    // drains vmcnt(0): tiles visible
        #pragma unroll
        for (int kk = 0; kk < 64; kk += 32) {
            short8 a[4], b[4];
            const int coloff = kk * 2 + lk * 16;
            #pragma unroll
            for (int mi = 0; mi < 4; ++mi)
                a[mi] = *(const short8*)((const char*)Al + swz(wm + mi * 16 + lr, coloff));
            #pragma unroll
            for (int ni = 0; ni < 4; ++ni)
                b[ni] = *(const short8*)((const char*)Bl + swz(wn + ni * 16 + lr, coloff));
            #pragma unroll
            for (int mi = 0; mi < 4; ++mi)
                #pragma unroll
                for (int ni = 0; ni < 4; ++ni)
                    acc[mi][ni] = __builtin_amdgcn_mfma_f32_16x16x32_bf16(a[mi], b[ni], acc[mi][ni], 0, 0, 0);
        }
    }
    // epilogue: D row=(lane>>4)*4+r, col=lane&15
    #pragma unroll
    for (int mi = 0; mi < 4; ++mi) {
        #pragma unroll
        for (int ni = 0; ni < 4; ++ni) {
            const int col = n0 + wn + ni * 16 + lr;
            #pragma unroll
            for (int r = 0; r < 4; ++r) {
                const int rowg = m0 + wm + mi * 16 + lk * 4 + r;
                if (rowg < NN) y[(size_t)rowg * KOUT + col] = f2bf(acc[mi][ni][r]);
            }
        }
    }
}

// ---------------- Phase 1 v2 (reg-staged, fused convert) — fallback path
__global__ __launch_bounds__(256) void gemm_v2(const float* __restrict__ x,
                                               const unsigned short* __restrict__ wsB,
                                               unsigned short* __restrict__ y) {
    __shared__ unsigned short Al[128 * 64];
    __shared__ unsigned short Bl[128 * 64];
    const int tid = threadIdx.x;
    const int logical = ((int)blockIdx.x & 7) * ((int)gridDim.x >> 3) + ((int)blockIdx.x >> 3);
    const int mt = logical >> 2, nt = logical & 3;
    const int m0 = mt * 128;
    const int lane = tid & 63, wid = tid >> 6;
    const int wm = (wid >> 1) * 64, wn = (wid & 1) * 64;
    const int lr = lane & 15, lk = lane >> 4;

    const int arow = tid >> 2;
    const int acolb = (tid & 3) * 16;
    int r0 = m0 + arow;       if (r0 > NN - 1) r0 = NN - 1;
    int r1 = m0 + 64 + arow;  if (r1 > NN - 1) r1 = NN - 1;
    const float* xr0 = x + (size_t)r0 * H + acolb;
    const float* xr1 = x + (size_t)r1 * H + acolb;
    const unsigned short* bt = wsB + nt * 4 * 8192 + tid * 8;

    float4 pA[2][4];
    ushort8v pB[4];
    auto loadA = [&](int ks) {
        const float* s0 = xr0 + ks * 64;
        const float* s1 = xr1 + ks * 64;
        #pragma unroll
        for (int q = 0; q < 4; ++q) pA[0][q] = *(const float4*)(s0 + q * 4);
        #pragma unroll
        for (int q = 0; q < 4; ++q) pA[1][q] = *(const float4*)(s1 + q * 4);
    };
    auto loadB = [&](int ks) {
        const unsigned short* s = bt + ks * 8192;
        #pragma unroll
        for (int u = 0; u < 4; ++u) pB[u] = *(const ushort8v*)(s + u * 2048);
    };
    auto stage = [&]() {
        #pragma unroll
        for (int p = 0; p < 2; ++p) {
            int row = arow + p * 64;
            ushort8v q0, q1;
            q0[0]=f2bf(pA[p][0].x); q0[1]=f2bf(pA[p][0].y); q0[2]=f2bf(pA[p][0].z); q0[3]=f2bf(pA[p][0].w);
            q0[4]=f2bf(pA[p][1].x); q0[5]=f2bf(pA[p][1].y); q0[6]=f2bf(pA[p][1].z); q0[7]=f2bf(pA[p][1].w);
            q1[0]=f2bf(pA[p][2].x); q1[1]=f2bf(pA[p][2].y); q1[2]=f2bf(pA[p][2].z); q1[3]=f2bf(pA[p][2].w);
            q1[4]=f2bf(pA[p][3].x); q1[5]=f2bf(pA[p][3].y); q1[6]=f2bf(pA[p][3].z); q1[7]=f2bf(pA[p][3].w);
            *(ushort8v*)((char*)Al + swz(row, acolb * 2))      = q0;
            *(ushort8v*)((char*)Al + swz(row, acolb * 2 + 16)) = q1;
        }
        #pragma unroll
        for (int u = 0; u < 4; ++u) *(ushort8v*)(Bl + tid * 8 + u * 2048) = pB[u];
    };

    f32x4 acc[4][4] = {};
    loadA(0); loadB(0);
    #pragma unroll
    for (int ks = 0; ks < 4; ++ks) {
        stage();
        __syncthreads();
        if (ks < 3) { loadA(ks + 1); loadB(ks + 1); }
        #pragma unroll
        for (int kk = 0; kk < 64; kk += 32) {
            short8 a[4], b[4];
            const int coloff = kk * 2 + lk * 16;
            #pragma unroll
            for (int mi = 0; mi < 4; ++mi)
                a[mi] = *(const short8*)((const char*)Al + swz(wm + mi * 16 + lr, coloff));
            #pragma unroll
            for (int ni = 0; ni < 4; ++ni)
                b[ni] = *(const short8*)((const char*)Bl + swz(wn + ni * 16 + lr, coloff));
            #pragma unroll
            for (int mi = 0; mi < 4; ++mi)
                #pragma unroll
                for (int ni = 0; ni < 4; ++ni)
                    acc[mi][ni] = __builtin_amdgcn_mfma_f32_16x16x32_bf16(a[mi], b[ni], acc[mi][ni], 0, 0, 0);
        }
        if (ks < 3) {
            asm volatile("s_waitcnt lgkmcnt(0)" ::: "memory");
            __builtin_amdgcn_s_barrier();
            __builtin_amdgcn_sched_barrier(0);
        }
    }
    const int n0 = nt * 128;
    #pragma unroll
    for (int mi = 0; mi < 4; ++mi)
        #pragma unroll
        for (int ni = 0; ni < 4; ++ni) {
            const int col = n0 + wn + ni * 16 + lr;
            #pragma unroll
            for (int r = 0; r < 4; ++r) {
                const int rowg = m0 + wm + mi * 16 + lk * 4 + r;
                if (rowg < NN) y[(size_t)rowg * KOUT + col] = f2bf(acc[mi][ni][r]);
            }
        }
}

// ---------------- Phase 2: half-wave per edge, ushort8 gathers
__global__ __launch_bounds__(256) void edge_v2(const unsigned short* __restrict__ y,
                                               const int* __restrict__ ei,
                                               const float* __restrict__ b1,
                                               const float* __restrict__ W2,
                                               const float* __restrict__ b2,
                                               float* __restrict__ out) {
    const int tid = threadIdx.x;
    const int l32 = tid & 31;
    const int ghw = ((int)(blockIdx.x * blockDim.x) + tid) >> 5;
    const int nhw = ((int)(gridDim.x * blockDim.x)) >> 5;
    const int j = l32 * 8;
    const float4 b01 = *(const float4*)(b1 + j);
    const float4 b23 = *(const float4*)(b1 + j + 4);
    const float4 w01 = *(const float4*)(W2 + j);
    const float4 w23 = *(const float4*)(W2 + j + 4);
    const float bb = b2[0];
    #pragma unroll 2
    for (int e = ghw; e < NE; e += nhw) {
        int s = ei[e], d = ei[NE + e];
        s = s < 0 ? 0 : (s > NN - 1 ? NN - 1 : s);
        d = d < 0 ? 0 : (d > NN - 1 ? NN - 1 : d);
        ushort8v us = *(const ushort8v*)(y + (size_t)s * KOUT + j);
        ushort8v ud = *(const ushort8v*)(y + (size_t)d * KOUT + 256 + j);
        float acc;
        acc  = fmaxf(bf2f(us[0]) + bf2f(ud[0]) + b01.x, 0.f) * w01.x;
        acc += fmaxf(bf2f(us[1]) + bf2f(ud[1]) + b01.y, 0.f) * w01.y;
        acc += fmaxf(bf2f(us[2]) + bf2f(ud[2]) + b01.z, 0.f) * w01.z;
        acc += fmaxf(bf2f(us[3]) + bf2f(ud[3]) + b01.w, 0.f) * w01.w;
        acc += fmaxf(bf2f(us[4]) + bf2f(ud[4]) + b23.x, 0.f) * w23.x;
        acc += fmaxf(bf2f(us[5]) + bf2f(ud[5]) + b23.y, 0.f) * w23.y;
        acc += fmaxf(bf2f(us[6]) + bf2f(ud[6]) + b23.z, 0.f) * w23.z;
        acc += fmaxf(bf2f(us[7]) + bf2f(ud[7]) + b23.w, 0.f) * w23.w;
        #pragma unroll
        for (int off = 16; off > 0; off >>= 1) acc += __shfl_xor(acc, off, 64);
        if (l32 == 0) out[e] = acc + bb;
    }
}

// ---------------- Fallback (ws too small): fused wave-per-edge, fp32. Slow but correct.
__global__ __launch_bounds__(256) void fused_fallback(const float* __restrict__ x,
                                                      const int* __restrict__ ei,
                                                      const float* __restrict__ W1,
                                                      const float* __restrict__ b1,
                                                      const float* __restrict__ W2,
                                                      const float* __restrict__ b2,
                                                      float* __restrict__ out) {
    __shared__ float xsh[4][512];
    const int lane = threadIdx.x & 63;
    const int wl = threadIdx.x >> 6;
    const int gw = (blockIdx.x * blockDim.x + threadIdx.x) >> 6;
    const int nw = (gridDim.x * blockDim.x) >> 6;
    const int j = lane * 4;
    const float4 bv = *(const float4*)(b1 + j);
    const float4 wv = *(const float4*)(W2 + j);
    const float bb = b2[0];
    for (int e = gw; e < NE; e += nw) {
        int s = ei[e], d = ei[NE + e];
        s = min(max(s, 0), NN - 1);
        d = min(max(d, 0), NN - 1);
        __threadfence_block();
        #pragma unroll
        for (int i = 0; i < 4; ++i) {
            xsh[wl][i * 64 + lane]       = x[(size_t)s * H + i * 64 + lane];
            xsh[wl][256 + i * 64 + lane] = x[(size_t)d * H + i * 64 + lane];
        }
        __threadfence_block();
        float h0 = bv.x, h1 = bv.y, h2 = bv.z, h3 = bv.w;
        for (int k = 0; k < 256; ++k) {
            float xa = xsh[wl][k], xb2 = xsh[wl][256 + k];
            float4 wa = *(const float4*)(W1 + (size_t)k * 256 + j);
            float4 wb = *(const float4*)(W1 + (size_t)(k + 256) * 256 + j);
            h0 += xa * wa.x + xb2 * wb.x;
            h1 += xa * wa.y + xb2 * wb.y;
            h2 += xa * wa.z + xb2 * wb.z;
            h3 += xa * wa.w + xb2 * wb.w;
        }
        float acc = fmaxf(h0, 0.f) * wv.x + fmaxf(h1, 0.f) * wv.y +
                    fmaxf(h2, 0.f) * wv.z + fmaxf(h3, 0.f) * wv.w;
        #pragma unroll
        for (int off = 32; off > 0; off >>= 1) acc += __shfl_xor(acc, off, 64);
        if (lane == 0) out[e] = acc + bb;
    }
}

extern "C" void kernel_launch(void* const* d_in, const int* in_sizes, int n_in,
                              void* d_out, int out_size, void* d_ws, size_t ws_size,
                              hipStream_t stream) {
    const float* x  = (const float*)d_in[0];
    const int*   ei = (const int*)d_in[1];
    const float* W1 = (const float*)d_in[2];
    const float* b1 = (const float*)d_in[3];
    const float* W2 = (const float*)d_in[4];
    const float* b2 = (const float*)d_in[5];
    float* out = (float*)d_out;

    const size_t ybytes  = (size_t)NN * KOUT * sizeof(unsigned short);      // 102.4 MB
    const size_t xbbytes = (size_t)MTILES * 4 * 16384;                      // 51.25 MB
    const size_t wbytes  = 16 * 8192 * sizeof(unsigned short);              // 256 KB

    if (ws_size >= ybytes + xbbytes + wbytes) {
        unsigned short* yb  = (unsigned short*)d_ws;
        unsigned short* xbb = (unsigned short*)((char*)d_ws + ybytes);
        unsigned short* wb  = (unsigned short*)((char*)d_ws + ybytes + xbbytes);
        wprep<<<dim3(64), dim3(256), 0, stream>>>(W1, wb);
        xprep<<<dim3(MTILES * 4 * 4), dim3(256), 0, stream>>>(x, xbb);
        gemm_v3<<<dim3(MTILES * 4), dim3(256), 0, stream>>>(xbb, wb, yb);
        edge_v2<<<dim3(2048), dim3(256), 0, stream>>>(yb, ei, b1, W2, b2, out);
    } else if (ws_size >= ybytes + wbytes) {
        unsigned short* yb = (unsigned short*)d_ws;
        unsigned short* wb = (unsigned short*)((char*)d_ws + ybytes);
        wprep<<<dim3(64), dim3(256), 0, stream>>>(W1, wb);
        gemm_v2<<<dim3(MTILES * 4), dim3(256), 0, stream>>>(x, wb, yb);
        edge_v2<<<dim3(2048), dim3(256), 0, stream>>>(yb, ei, b1, W2, b2, out);
    } else {
        fused_fallback<<<dim3(2048), dim3(256), 0, stream>>>(x, ei, W1, b1, W2, b2, out);
    }
}